// Round 18
// baseline (254.667 us; speedup 1.0000x reference)
//
#include <hip/hip_runtime.h>
#include <cstdint>
#include <cstddef>

#define B_ 16
#define C_ 64
#define N_ 2048
#define K_ 20
#define CANDH 24
#define CAND_T 48
#define LQ 12

typedef short bf16x8 __attribute__((ext_vector_type(8)));
typedef float f32x4 __attribute__((ext_vector_type(4)));

__device__ __forceinline__ unsigned umin_(unsigned a, unsigned b) { return a < b ? a : b; }
__device__ __forceinline__ unsigned umax_(unsigned a, unsigned b) { return a > b ? a : b; }
__device__ __forceinline__ unsigned short bfr_(float v) {
    unsigned u = __float_as_uint(v);
    return (unsigned short)((u + 0x7FFFu + ((u >> 16) & 1u)) >> 16);
}

// K1 (lean): sqf = np.sum(xt*xt,-1) bit-exact (pairwise 8-acc tree);
// xh = bf16 rows, c-blocks XOR-swizzled; xrT = f32 contiguous rows.
__global__ __launch_bounds__(128) void k_sq(const float* __restrict__ x,
                                            float* __restrict__ sqf,
                                            unsigned short* __restrict__ xh,
                                            float* __restrict__ xrT) {
    int tid = threadIdx.x;
    int i = blockIdx.x * 128 + tid;   // 0..B_*N_-1
    int b = i >> 11, n = i & (N_ - 1);
    const float* xb = x + (size_t)b * C_ * N_ + n;
    float vr[C_];
#pragma unroll
    for (int c = 0; c < C_; ++c) vr[c] = xb[(size_t)c * N_];
    float p[C_];
#pragma unroll
    for (int c = 0; c < C_; ++c) p[c] = __fmul_rn(vr[c], vr[c]);
    float r[8];
#pragma unroll
    for (int k = 0; k < 8; ++k) r[k] = p[k];
#pragma unroll
    for (int ii = 8; ii < 64; ii += 8) {
#pragma unroll
        for (int k = 0; k < 8; ++k) r[k] = __fadd_rn(r[k], p[ii + k]);
    }
    float s0 = __fadd_rn(__fadd_rn(r[0], r[1]), __fadd_rn(r[2], r[3]));
    float s1 = __fadd_rn(__fadd_rn(r[4], r[5]), __fadd_rn(r[6], r[7]));
    sqf[i] = __fadd_rn(s0, s1);

    unsigned short* xrow = xh + (size_t)i * 64;
#pragma unroll
    for (int cb = 0; cb < 8; ++cb) {
        bf16x8 pk;
#pragma unroll
        for (int e = 0; e < 8; ++e) pk[e] = (short)bfr_(vr[cb * 8 + e]);
        *reinterpret_cast<bf16x8*>(xrow + ((cb ^ (n & 7)) * 8)) = pk;
    }
    if (xrT) {
        float4* dst = reinterpret_cast<float4*>(xrT + (size_t)i * C_);
#pragma unroll
        for (int q = 0; q < 16; ++q)
            dst[q] = make_float4(vr[q*4+0], vr[q*4+1], vr[q*4+2], vr[q*4+3]);
    }
}

// K2a: MFMA distance pass, m-split x2 for occupancy (4 blocks/CU, 16 w/CU).
// Block = 64 rows x 1024 ms (4 tiles of 256); med3 sorted-insert; AGPR ban;
// each half extracts its own top-24 into candu[.. half*24 ..].
__global__ __launch_bounds__(256, 4) void k_dist(const unsigned short* __restrict__ xh,
                                                 const float* __restrict__ sqf,
                                                 unsigned short* __restrict__ candu) {
    __shared__ __align__(16) unsigned short xtl[256 * 64];   // 32 KB
    __shared__ float sqm[256];
    int tid = threadIdx.x;
    int w = tid >> 6, lane = tid & 63;
    int bid = blockIdx.x;             // B_*64 = 1024
    int b = bid >> 6;
    int g = bid & 63;
    int n0 = (g >> 1) * 64;
    int half = g & 1;
    int mbase = half * 1024;
    const unsigned short* xhb = xh + (size_t)b * N_ * 64;

    {
#pragma unroll
        for (int i = 0; i < 2; ++i) {
            int ch = tid + 256 * i;
            *reinterpret_cast<uint4*>(&xtl[ch * 8]) =
                *reinterpret_cast<const uint4*>(&xhb[(size_t)n0 * 64 + ch * 8]);
        }
    }
    __syncthreads();
    int rl = w * 16 + (lane & 15);
    int cb0 = (lane >> 4), cb1 = 4 + (lane >> 4);
    bf16x8 afr0 = *reinterpret_cast<const bf16x8*>(&xtl[rl * 64 + ((cb0 ^ (lane & 7)) * 8)]);
    bf16x8 afr1 = *reinterpret_cast<const bf16x8*>(&xtl[rl * 64 + ((cb1 ^ (lane & 7)) * 8)]);
    float rsq[4];
#pragma unroll
    for (int r = 0; r < 4; ++r)
        rsq[r] = sqf[b * N_ + n0 + w * 16 + (lane >> 4) * 4 + r];

    unsigned list[4][LQ];
#pragma unroll
    for (int r = 0; r < 4; ++r)
#pragma unroll
        for (int j = 0; j < LQ; ++j) list[r][j] = 0xFFFFFFFFu;

    unsigned kmask = 0xFFFFF800u;

    for (int t = 0; t < 4; ++t) {
        int m0 = mbase + t * 256;
        __syncthreads();
        {
#pragma unroll
            for (int i = 0; i < 8; ++i) {
                int ch = tid + 256 * i;
                *reinterpret_cast<uint4*>(&xtl[ch * 8]) =
                    *reinterpret_cast<const uint4*>(&xhb[(size_t)m0 * 64 + ch * 8]);
            }
            sqm[tid] = sqf[b * N_ + m0 + tid];
        }
        __syncthreads();
        // AGPR-home ban: anything live across this point stays in arch VGPRs.
        asm volatile("" :::
            "a0","a1","a2","a3","a4","a5","a6","a7",
            "a8","a9","a10","a11","a12","a13","a14","a15",
            "a16","a17","a18","a19","a20","a21","a22","a23",
            "a24","a25","a26","a27","a28","a29","a30","a31",
            "a32","a33","a34","a35","a36","a37","a38","a39",
            "a40","a41","a42","a43","a44","a45","a46","a47",
            "a48","a49","a50","a51","a52","a53","a54","a55",
            "a56","a57","a58","a59","a60","a61","a62","a63",
            "a64","a65","a66","a67","a68","a69","a70","a71",
            "a72","a73","a74","a75","a76","a77","a78","a79",
            "a80","a81","a82","a83","a84","a85","a86","a87",
            "a88","a89","a90","a91","a92","a93","a94","a95");
        const unsigned short* pB0 = &xtl[(lane & 15) * 64 + ((cb0 ^ (lane & 7)) * 8)];
        const unsigned short* pB1 = &xtl[(lane & 15) * 64 + ((cb1 ^ (lane & 7)) * 8)];
        const float* pS = &sqm[lane & 15];
#pragma unroll
        for (int mb = 0; mb < 16; ++mb) {
            bf16x8 bf0 = *reinterpret_cast<const bf16x8*>(pB0 + mb * 1024);
            bf16x8 bf1 = *reinterpret_cast<const bf16x8*>(pB1 + mb * 1024);
            f32x4 acc = {0.f, 0.f, 0.f, 0.f};
            acc = __builtin_amdgcn_mfma_f32_16x16x32_bf16(afr0, bf0, acc, 0, 0, 0);
            acc = __builtin_amdgcn_mfma_f32_16x16x32_bf16(afr1, bf1, acc, 0, 0, 0);
            float smv = pS[mb * 16];
            unsigned mg = (unsigned)(m0 + mb * 16) | (unsigned)(lane & 15);
#pragma unroll
            for (int r = 0; r < 4; ++r) {
                float rs = rsq[r] + smv;
                float d = fmaf(-2.f, acc[r], rs);
                d = fmaxf(d, 0.f);   // d>=0: IEEE bits are unsigned-monotone
                unsigned key;
                asm("v_bfi_b32 %0, %1, %2, %3"
                    : "=v"(key) : "v"(kmask), "v"(__float_as_uint(d)), "v"(mg));
#pragma unroll
                for (int j = LQ - 1; j > 0; --j)
                    asm("v_med3_u32 %0, %0, %1, %2"
                        : "+v"(list[r][j])
                        : "v"(list[r][j - 1]), "v"(key));
                list[r][0] = umin_(list[r][0], key);
            }
        }
    }

    size_t grow0 = (size_t)b * N_ + n0 + w * 16 + (lane >> 4) * 4;
#pragma unroll 1
    for (int it = 0; it < CANDH; ++it) {
        unsigned head[4], wv[4];
#pragma unroll
        for (int j = 0; j < 4; ++j) { head[j] = list[j][0]; wv[j] = head[j]; }
#pragma unroll
        for (int d2 = 1; d2 < 16; d2 <<= 1)
#pragma unroll
            for (int j = 0; j < 4; ++j)
                wv[j] = umin_(wv[j], (unsigned)__shfl_xor((int)wv[j], d2, 16));
#pragma unroll
        for (int j = 0; j < 4; ++j) {
            bool own = (head[j] == wv[j]);
#pragma unroll
            for (int jj = 0; jj < LQ - 1; ++jj)
                list[j][jj] = own ? list[j][jj + 1] : list[j][jj];
            list[j][LQ - 1] = own ? 0xFFFFFFFFu : list[j][LQ - 1];
            if ((lane & 15) == 0)
                candu[(grow0 + j) * CAND_T + half * CANDH + it] =
                    (unsigned short)(wv[j] & 2047u);
        }
    }
}

// shared bodies for rescore3 / k_y --------------------------------------

struct ShR { float xnl[64 * 64]; unsigned short cl[64 * CAND_T]; float dl2[64][CAND_T]; };
struct ShY { float Al[C_ * 64]; float xl[C_ * 64]; };

__device__ __forceinline__ void rescore3_body(ShR& s, int bid, int tid,
                                              const float* __restrict__ xrT,
                                              const float* __restrict__ sqf,
                                              const unsigned short* __restrict__ candu,
                                              float* __restrict__ idxf) {
    int lane = tid & 63, w = tid >> 6;
    int b = bid >> 5;
    int n0 = (bid & 31) * 64;
    int bN = b * N_;
    const float* xr = xrT + (size_t)bN * C_;
    {
        const float4* src = reinterpret_cast<const float4*>(xr + (size_t)n0 * C_);
#pragma unroll
        for (int q = 0; q < 4; ++q) {
            int idx = tid + q * 256;
            reinterpret_cast<float4*>(s.xnl)[idx] = src[idx];
        }
        // candu for 64 rows: 3072 u16 = 384 uint4
#pragma unroll
        for (int q = 0; q < 2; ++q) {
            int idx = tid + q * 256;
            if (idx < 384)
                reinterpret_cast<uint4*>(s.cl)[idx] =
                    reinterpret_cast<const uint4*>(candu + (size_t)(bN + n0) * CAND_T)[idx];
        }
    }
    __syncthreads();
    int qbase = lane & ~3, qr = lane & 3;
#pragma unroll 1
    for (int si = 0; si < 12; ++si) {
        int task = w * 768 + si * 64 + lane;   // 0..3071
        int row = task / CAND_T, ci = task - row * CAND_T;
        int m = s.cl[row * CAND_T + ci];
        float4 buf[16];
#pragma unroll
        for (int r = 0; r < 4; ++r) {
            int mq = __shfl(m, qbase + r, 64);
            const float* xmq = xr + (size_t)mq * C_ + qr * 16;
            float4 c0 = *reinterpret_cast<const float4*>(xmq + 0);
            float4 c1 = *reinterpret_cast<const float4*>(xmq + 4);
            float4 c2 = *reinterpret_cast<const float4*>(xmq + 8);
            float4 c3 = *reinterpret_cast<const float4*>(xmq + 12);
#pragma unroll
            for (int j2 = 0; j2 < 4; ++j2) {
                float4 s0, s1, s2, s3;
                s0.x = __shfl(c0.x, qbase + j2, 64);
                s0.y = __shfl(c0.y, qbase + j2, 64);
                s0.z = __shfl(c0.z, qbase + j2, 64);
                s0.w = __shfl(c0.w, qbase + j2, 64);
                s1.x = __shfl(c1.x, qbase + j2, 64);
                s1.y = __shfl(c1.y, qbase + j2, 64);
                s1.z = __shfl(c1.z, qbase + j2, 64);
                s1.w = __shfl(c1.w, qbase + j2, 64);
                s2.x = __shfl(c2.x, qbase + j2, 64);
                s2.y = __shfl(c2.y, qbase + j2, 64);
                s2.z = __shfl(c2.z, qbase + j2, 64);
                s2.w = __shfl(c2.w, qbase + j2, 64);
                s3.x = __shfl(c3.x, qbase + j2, 64);
                s3.y = __shfl(c3.y, qbase + j2, 64);
                s3.z = __shfl(c3.z, qbase + j2, 64);
                s3.w = __shfl(c3.w, qbase + j2, 64);
                if (qr == r) {
                    buf[j2 * 4 + 0] = s0;
                    buf[j2 * 4 + 1] = s1;
                    buf[j2 * 4 + 2] = s2;
                    buf[j2 * 4 + 3] = s3;
                }
            }
        }
        const float* xn = s.xnl + row * 64;
        float a = 0.f;
#pragma unroll
        for (int cq = 0; cq < 16; ++cq) {
            float4 n4 = *reinterpret_cast<const float4*>(xn + cq * 4);
            float4 m4 = buf[cq];
            a = __fadd_rn(a, __fmul_rn(n4.x, m4.x));
            a = __fadd_rn(a, __fmul_rn(n4.y, m4.y));
            a = __fadd_rn(a, __fmul_rn(n4.z, m4.z));
            a = __fadd_rn(a, __fmul_rn(n4.w, m4.w));
        }
        s.dl2[row][ci] = __fadd_rn(__fsub_rn(sqf[bN + n0 + row], __fmul_rn(2.0f, a)),
                                   sqf[bN + m]);
    }
    __syncthreads();
#pragma unroll 1
    for (int t2 = 0; t2 < 12; ++t2) {
        int task = tid + t2 * 256;
        int row = task / CAND_T, ci = task - row * CAND_T;
        int m = s.cl[row * CAND_T + ci];
        float di = s.dl2[row][ci];
        int rank = 0;
#pragma unroll
        for (int j = 0; j < CAND_T; ++j) {
            float dj = s.dl2[row][j];
            int mj = s.cl[row * CAND_T + j];
            rank += (dj < di || (dj == di && mj < m)) ? 1 : 0;
        }
        if (rank < K_)
            idxf[((size_t)bN + n0 + row) * K_ + rank] = (float)m;
    }
}

__device__ __forceinline__ void ky_body(ShY& s, int bid, int tid,
                                        const float* __restrict__ x,
                                        const float* __restrict__ W,
                                        float* __restrict__ Yt) {
    int b = bid >> 5;
    int m0 = (bid & 31) * 64;
    {
        int o = tid & 63, cb = tid >> 6;
#pragma unroll
        for (int j = 0; j < 16; ++j) {
            int c = cb * 16 + j;
            s.Al[c * 64 + o] = W[o * 128 + c] - W[o * 128 + 64 + c];
            s.xl[c * 64 + o] = x[((size_t)b * C_ + c) * N_ + m0 + o];
        }
    }
    __syncthreads();
    int ml = tid & 63, og = tid >> 6;
    float acc[16];
#pragma unroll
    for (int j = 0; j < 16; ++j) acc[j] = 0.f;
#pragma unroll 4
    for (int c = 0; c < C_; ++c) {
        float xv = s.xl[c * 64 + ml];
        const float4* a4 = reinterpret_cast<const float4*>(&s.Al[c * 64 + og * 16]);
#pragma unroll
        for (int q = 0; q < 4; ++q) {
            float4 av = a4[q];
            acc[q*4+0] = fmaf(av.x, xv, acc[q*4+0]);
            acc[q*4+1] = fmaf(av.y, xv, acc[q*4+1]);
            acc[q*4+2] = fmaf(av.z, xv, acc[q*4+2]);
            acc[q*4+3] = fmaf(av.w, xv, acc[q*4+3]);
        }
    }
    float* yp = Yt + ((size_t)b * N_ + m0 + ml) * C_ + og * 16;
#pragma unroll
    for (int q = 0; q < 4; ++q)
        reinterpret_cast<float4*>(yp)[q] =
            make_float4(acc[q*4+0], acc[q*4+1], acc[q*4+2], acc[q*4+3]);
}

// K2b+K3 fat kernel (dedicated-Yt path): blocks [0,512) rescore,
// [512,1024) Y-GEMM. LDS overlaid via union.
__global__ __launch_bounds__(256) void k_post(const float* __restrict__ xrT,
                                              const float* __restrict__ sqf,
                                              const unsigned short* __restrict__ candu,
                                              float* __restrict__ idxf,
                                              const float* __restrict__ x,
                                              const float* __restrict__ W,
                                              float* __restrict__ Yt) {
    __shared__ union U { ShR r; ShY y; } su;
    int bid = blockIdx.x;
    int tid = threadIdx.x;
    if (bid < B_ * 32)
        rescore3_body(su.r, bid, tid, xrT, sqf, candu, idxf);
    else
        ky_body(su.y, bid - B_ * 32, tid, x, W, Yt);
}

// standalone versions for the fallback paths
__global__ __launch_bounds__(256) void k_rescore3(const float* __restrict__ xrT,
                                                  const float* __restrict__ sqf,
                                                  const unsigned short* __restrict__ candu,
                                                  float* __restrict__ idxf) {
    __shared__ ShR s;
    rescore3_body(s, blockIdx.x, threadIdx.x, xrT, sqf, candu, idxf);
}

__global__ __launch_bounds__(256) void k_y(const float* __restrict__ x,
                                           const float* __restrict__ W,
                                           float* __restrict__ Yt) {
    __shared__ ShY s;
    ky_body(s, blockIdx.x, threadIdx.x, x, W, Yt);
}

// K2b fallback (xrT unavailable): exact rescore from strided x.
__global__ __launch_bounds__(256) void k_rescore(const float* __restrict__ x,
                                                 const float* __restrict__ sqf,
                                                 const unsigned short* __restrict__ candu,
                                                 float* __restrict__ idxf) {
    int tid = threadIdx.x;
    int w = tid >> 6, lane = tid & 63;
    size_t grow = (size_t)blockIdx.x * 4 + w;
    int b = (int)(grow >> 11), n = (int)(grow & (N_ - 1));
    const float* xb = x + (size_t)b * C_ * N_;
    float d = 0.f;
    unsigned m = 0xFFFFFFFFu;
    if (lane < CAND_T) {
        m = candu[grow * CAND_T + lane];
        float a = 0.f;
#pragma unroll 8
        for (int c = 0; c < C_; ++c)
            a = __fadd_rn(a, __fmul_rn(xb[(size_t)c * N_ + n], xb[(size_t)c * N_ + m]));
        d = __fadd_rn(__fsub_rn(sqf[b * N_ + n], __fmul_rn(2.0f, a)), sqf[b * N_ + m]);
    }
    int rank = 0;
#pragma unroll 1
    for (int j = 0; j < CAND_T; ++j) {
        float dj = __shfl(d, j, 64);
        unsigned mj = (unsigned)__shfl((int)m, j, 64);
        if (lane < CAND_T && (dj < d || (dj == d && mj < m))) ++rank;
    }
    if (lane < CAND_T && rank < K_)
        idxf[grow * K_ + rank] = (float)m;
}

// K4: Phase A u-GEMM -> Phase B wave-cooperative coalesced Yt gather-max +
// BN/leaky -> Phase C transpose store. (r16-proven form)
__global__ __launch_bounds__(256) void k_out(const float* __restrict__ x,
                                             const float* __restrict__ W,
                                             const float* __restrict__ gamma,
                                             const float* __restrict__ beta,
                                             const float* __restrict__ rmean,
                                             const float* __restrict__ rvar,
                                             const float* __restrict__ Yt,
                                             const float* __restrict__ idxf,
                                             float* __restrict__ out) {
    __shared__ float Bl[C_ * 64];
    __shared__ float xl[C_ * 64];
    __shared__ float resl[64 * 65];
    __shared__ float sl[64], tl[64];
    int tid = threadIdx.x;
    int bid = blockIdx.x;
    int b = bid >> 5;
    int n0 = (bid & 31) * 64;
    {
        int o = tid & 63, cb = tid >> 6;
#pragma unroll
        for (int j = 0; j < 16; ++j) {
            int c = cb * 16 + j;
            Bl[c * 64 + o] = W[o * 128 + 64 + c];
            xl[c * 64 + o] = x[((size_t)b * C_ + c) * N_ + n0 + o];
        }
        if (tid < 64) {
            float s = gamma[tid] / sqrtf(rvar[tid] + 1e-5f);
            sl[tid] = s;
            tl[tid] = beta[tid] - rmean[tid] * s;
        }
    }
    __syncthreads();
    {
        int nl = tid & 63, wv2 = tid >> 6;
#pragma unroll
        for (int t = 0; t < 4; ++t) {
            int oq = wv2 * 4 + t;
            float ax = 0.f, ay = 0.f, az = 0.f, aw = 0.f;
#pragma unroll 8
            for (int c = 0; c < C_; ++c) {
                float xv = xl[c * 64 + nl];
                float4 bl4 = *reinterpret_cast<const float4*>(&Bl[c * 64 + oq * 4]);
                ax = fmaf(bl4.x, xv, ax);
                ay = fmaf(bl4.y, xv, ay);
                az = fmaf(bl4.z, xv, az);
                aw = fmaf(bl4.w, xv, aw);
            }
            int o0 = oq * 4;
            resl[(o0 + 0) * 65 + nl] = ax;
            resl[(o0 + 1) * 65 + nl] = ay;
            resl[(o0 + 2) * 65 + nl] = az;
            resl[(o0 + 3) * 65 + nl] = aw;
        }
    }
    __syncthreads();
    int* mil = reinterpret_cast<int*>(Bl);    // [64][20], Bl dead
    {
#pragma unroll
        for (int q = 0; q < 5; ++q) {
            int idx = tid + q * 256;
            mil[idx] = (int)idxf[(size_t)(b * N_ + n0) * K_ + idx];
        }
    }
    __syncthreads();
    {
        int w2 = tid >> 6, lane2 = tid & 63;
        const float* Ytb = Yt + (size_t)b * N_ * C_;
        float s = sl[lane2], t0 = tl[lane2];
        for (int i = 0; i < 16; ++i) {
            int nloc = w2 * 16 + i;
            float v = -3.4e38f;
#pragma unroll
            for (int k = 0; k < K_; ++k) {
                int m = mil[nloc * K_ + k];
                v = fmaxf(v, Ytb[(size_t)m * C_ + lane2]);
            }
            float u = resl[lane2 * 65 + nloc];
            float val = s * (u + v) + t0;
            val = val > 0.f ? val : 0.2f * val;
            resl[lane2 * 65 + nloc] = val;
        }
    }
    __syncthreads();
    {
        int nl2 = tid & 63, ob = tid >> 6;
#pragma unroll
        for (int j = 0; j < 16; ++j) {
            int o2 = ob * 16 + j;
            out[((size_t)b * C_ + o2) * N_ + n0 + nl2] = resl[o2 * 65 + nl2];
        }
    }
}

extern "C" void kernel_launch(void* const* d_in, const int* in_sizes, int n_in,
                              void* d_out, int out_size, void* d_ws, size_t ws_size,
                              hipStream_t stream) {
    const float* x     = (const float*)d_in[0];
    const float* W     = (const float*)d_in[1];
    const float* gamma = (const float*)d_in[2];
    const float* beta  = (const float*)d_in[3];
    const float* rmean = (const float*)d_in[4];
    const float* rvar  = (const float*)d_in[5];

    float* out  = (float*)d_out;                         // [16][64][2048]
    float* idxf = out + (size_t)B_ * C_ * N_;            // [16][2048][20] as floats

    char* ws = (char*)d_ws;
    // layout: sqf 128K | candu u16x48 3.0M | xh 4M | xrT 8M | [Yt 8M if room]
    float* sqf            = (float*)ws;
    unsigned short* candu = (unsigned short*)(ws + 131072);
    unsigned short* xh    = (unsigned short*)(ws + 131072 + 3145728);
    size_t off_xrT        = 131072 + 3145728 + 4194304;              // 7.47 MB
    size_t need_xrT       = off_xrT + 8388608;                       // 15,859,712 (r9-proven)
    size_t need_ded       = need_xrT + 8388608;                      // 24.25 MB
    float* xrT            = (ws_size >= need_xrT) ? (float*)(ws + off_xrT) : nullptr;
    bool dedY             = (ws_size >= need_ded);
    // fallback Yt aliases candu+xh (dead by the time k_y runs)
    float* Yt             = dedY ? (float*)(ws + need_xrT) : (float*)(ws + 131072);

    k_sq   <<<B_ * N_ / 128, 128, 0, stream>>>(x, sqf, xh, xrT);
    k_dist <<<B_ * 64, 256, 0, stream>>>(xh, sqf, candu);
    if (xrT && dedY) {
        k_post<<<B_ * 64, 256, 0, stream>>>(xrT, sqf, candu, idxf, x, W, Yt);
    } else if (xrT) {
        k_rescore3<<<B_ * 32, 256, 0, stream>>>(xrT, sqf, candu, idxf);
        k_y<<<B_ * 32, 256, 0, stream>>>(x, W, Yt);
    } else {
        k_rescore<<<B_ * N_ / 4, 256, 0, stream>>>(x, sqf, candu, idxf);
        k_y<<<B_ * 32, 256, 0, stream>>>(x, W, Yt);
    }
    k_out  <<<B_ * 32, 256, 0, stream>>>(x, W, gamma, beta, rmean, rvar, Yt, idxf, out);
}

// Round 19
// 151.846 us; speedup vs baseline: 1.6771x; 1.6771x over previous
//
#include <hip/hip_runtime.h>
#include <cstdint>
#include <cstddef>

#define B_ 16
#define C_ 64
#define N_ 2048
#define K_ 20
#define CAND 24
#define LQ 12

typedef short bf16x8 __attribute__((ext_vector_type(8)));
typedef float f32x4 __attribute__((ext_vector_type(4)));

__device__ __forceinline__ unsigned umin_(unsigned a, unsigned b) { return a < b ? a : b; }
__device__ __forceinline__ unsigned umax_(unsigned a, unsigned b) { return a > b ? a : b; }
__device__ __forceinline__ unsigned short bfr_(float v) {
    unsigned u = __float_as_uint(v);
    return (unsigned short)((u + 0x7FFFu + ((u >> 16) & 1u)) >> 16);
}

// K1 (lean): sqf = np.sum(xt*xt,-1) bit-exact (pairwise 8-acc tree);
// xh = bf16 rows, c-blocks XOR-swizzled; xrT = f32 contiguous rows.
__global__ __launch_bounds__(128) void k_sq(const float* __restrict__ x,
                                            float* __restrict__ sqf,
                                            unsigned short* __restrict__ xh,
                                            float* __restrict__ xrT) {
    int tid = threadIdx.x;
    int i = blockIdx.x * 128 + tid;   // 0..B_*N_-1
    int b = i >> 11, n = i & (N_ - 1);
    const float* xb = x + (size_t)b * C_ * N_ + n;
    float vr[C_];
#pragma unroll
    for (int c = 0; c < C_; ++c) vr[c] = xb[(size_t)c * N_];
    float p[C_];
#pragma unroll
    for (int c = 0; c < C_; ++c) p[c] = __fmul_rn(vr[c], vr[c]);
    float r[8];
#pragma unroll
    for (int k = 0; k < 8; ++k) r[k] = p[k];
#pragma unroll
    for (int ii = 8; ii < 64; ii += 8) {
#pragma unroll
        for (int k = 0; k < 8; ++k) r[k] = __fadd_rn(r[k], p[ii + k]);
    }
    float s0 = __fadd_rn(__fadd_rn(r[0], r[1]), __fadd_rn(r[2], r[3]));
    float s1 = __fadd_rn(__fadd_rn(r[4], r[5]), __fadd_rn(r[6], r[7]));
    sqf[i] = __fadd_rn(s0, s1);

    unsigned short* xrow = xh + (size_t)i * 64;
#pragma unroll
    for (int cb = 0; cb < 8; ++cb) {
        bf16x8 pk;
#pragma unroll
        for (int e = 0; e < 8; ++e) pk[e] = (short)bfr_(vr[cb * 8 + e]);
        *reinterpret_cast<bf16x8*>(xrow + ((cb ^ (n & 7)) * 8)) = pk;
    }
    if (xrT) {
        float4* dst = reinterpret_cast<float4*>(xrT + (size_t)i * C_);
#pragma unroll
        for (int q = 0; q < 16; ++q)
            dst[q] = make_float4(vr[q*4+0], vr[q*4+1], vr[q*4+2], vr[q*4+3]);
    }
}

// K2a: MFMA distance pass. r16 structure + (a) AGPR-home ban (clobber a0-a95
// each tile: values live across it — the lists, A-frags — must live in arch
// VGPRs), (b) v_bfi key pack. (r17-proven, 67 µs)
__global__ __launch_bounds__(256, 2) void k_dist(const unsigned short* __restrict__ xh,
                                                 const float* __restrict__ sqf,
                                                 unsigned short* __restrict__ candu) {
    __shared__ __align__(16) unsigned short xtl[256 * 64];   // 32 KB
    __shared__ float sqm[256];
    int tid = threadIdx.x;
    int w = tid >> 6, lane = tid & 63;
    int bid = blockIdx.x;             // B_*32 = 512
    int b = bid >> 5;
    int n0 = (bid & 31) * 64;
    const unsigned short* xhb = xh + (size_t)b * N_ * 64;

    {
#pragma unroll
        for (int i = 0; i < 2; ++i) {
            int ch = tid + 256 * i;
            *reinterpret_cast<uint4*>(&xtl[ch * 8]) =
                *reinterpret_cast<const uint4*>(&xhb[(size_t)n0 * 64 + ch * 8]);
        }
    }
    __syncthreads();
    int rl = w * 16 + (lane & 15);
    int cb0 = (lane >> 4), cb1 = 4 + (lane >> 4);
    bf16x8 afr0 = *reinterpret_cast<const bf16x8*>(&xtl[rl * 64 + ((cb0 ^ (lane & 7)) * 8)]);
    bf16x8 afr1 = *reinterpret_cast<const bf16x8*>(&xtl[rl * 64 + ((cb1 ^ (lane & 7)) * 8)]);
    float rsq[4];
#pragma unroll
    for (int r = 0; r < 4; ++r)
        rsq[r] = sqf[b * N_ + n0 + w * 16 + (lane >> 4) * 4 + r];

    unsigned list[4][LQ];
#pragma unroll
    for (int r = 0; r < 4; ++r)
#pragma unroll
        for (int j = 0; j < LQ; ++j) list[r][j] = 0xFFFFFFFFu;

    unsigned kmask = 0xFFFFF800u;

    for (int t = 0; t < 8; ++t) {
        int m0 = t * 256;
        __syncthreads();
        {
#pragma unroll
            for (int i = 0; i < 8; ++i) {
                int ch = tid + 256 * i;
                *reinterpret_cast<uint4*>(&xtl[ch * 8]) =
                    *reinterpret_cast<const uint4*>(&xhb[(size_t)m0 * 64 + ch * 8]);
            }
            sqm[tid] = sqf[b * N_ + m0 + tid];
        }
        __syncthreads();
        // AGPR-home ban: anything live across this point must be in arch VGPRs.
        asm volatile("" :::
            "a0","a1","a2","a3","a4","a5","a6","a7",
            "a8","a9","a10","a11","a12","a13","a14","a15",
            "a16","a17","a18","a19","a20","a21","a22","a23",
            "a24","a25","a26","a27","a28","a29","a30","a31",
            "a32","a33","a34","a35","a36","a37","a38","a39",
            "a40","a41","a42","a43","a44","a45","a46","a47",
            "a48","a49","a50","a51","a52","a53","a54","a55",
            "a56","a57","a58","a59","a60","a61","a62","a63",
            "a64","a65","a66","a67","a68","a69","a70","a71",
            "a72","a73","a74","a75","a76","a77","a78","a79",
            "a80","a81","a82","a83","a84","a85","a86","a87",
            "a88","a89","a90","a91","a92","a93","a94","a95");
        const unsigned short* pB0 = &xtl[(lane & 15) * 64 + ((cb0 ^ (lane & 7)) * 8)];
        const unsigned short* pB1 = &xtl[(lane & 15) * 64 + ((cb1 ^ (lane & 7)) * 8)];
        const float* pS = &sqm[lane & 15];
#pragma unroll
        for (int mb = 0; mb < 16; ++mb) {
            bf16x8 bf0 = *reinterpret_cast<const bf16x8*>(pB0 + mb * 1024);
            bf16x8 bf1 = *reinterpret_cast<const bf16x8*>(pB1 + mb * 1024);
            f32x4 acc = {0.f, 0.f, 0.f, 0.f};
            acc = __builtin_amdgcn_mfma_f32_16x16x32_bf16(afr0, bf0, acc, 0, 0, 0);
            acc = __builtin_amdgcn_mfma_f32_16x16x32_bf16(afr1, bf1, acc, 0, 0, 0);
            float smv = pS[mb * 16];
            unsigned mg = (unsigned)(m0 + mb * 16) | (unsigned)(lane & 15);
#pragma unroll
            for (int r = 0; r < 4; ++r) {
                float rs = rsq[r] + smv;
                float d = fmaf(-2.f, acc[r], rs);
                d = fmaxf(d, 0.f);   // d>=0: IEEE bits are unsigned-monotone
                unsigned key;
                asm("v_bfi_b32 %0, %1, %2, %3"
                    : "=v"(key) : "v"(kmask), "v"(__float_as_uint(d)), "v"(mg));
#pragma unroll
                for (int j = LQ - 1; j > 0; --j)
                    asm("v_med3_u32 %0, %0, %1, %2"
                        : "+v"(list[r][j])
                        : "v"(list[r][j - 1]), "v"(key));
                list[r][0] = umin_(list[r][0], key);
            }
        }
    }

    size_t grow0 = (size_t)b * N_ + n0 + w * 16 + (lane >> 4) * 4;
#pragma unroll 1
    for (int it = 0; it < CAND; ++it) {
        unsigned head[4], wv[4];
#pragma unroll
        for (int j = 0; j < 4; ++j) { head[j] = list[j][0]; wv[j] = head[j]; }
#pragma unroll
        for (int d2 = 1; d2 < 16; d2 <<= 1)
#pragma unroll
            for (int j = 0; j < 4; ++j)
                wv[j] = umin_(wv[j], (unsigned)__shfl_xor((int)wv[j], d2, 16));
#pragma unroll
        for (int j = 0; j < 4; ++j) {
            bool own = (head[j] == wv[j]);
#pragma unroll
            for (int jj = 0; jj < LQ - 1; ++jj)
                list[j][jj] = own ? list[j][jj + 1] : list[j][jj];
            list[j][LQ - 1] = own ? 0xFFFFFFFFu : list[j][LQ - 1];
            if ((lane & 15) == 0)
                candu[(grow0 + j) * CAND + it] = (unsigned short)(wv[j] & 2047u);
        }
    }
}

// shared bodies for rescore3 / k_y --------------------------------------

struct ShR { float xnl[64 * 64]; unsigned short cl[64 * CAND]; float dl2[64][CAND]; };
struct ShY { float Al[C_ * 64]; float xl[C_ * 64]; };

__device__ __forceinline__ void rescore3_body(ShR& s, int bid, int tid,
                                              const float* __restrict__ xrT,
                                              const float* __restrict__ sqf,
                                              const unsigned short* __restrict__ candu,
                                              float* __restrict__ idxf) {
    int lane = tid & 63, w = tid >> 6;
    int b = bid >> 5;
    int n0 = (bid & 31) * 64;
    int bN = b * N_;
    const float* xr = xrT + (size_t)bN * C_;
    {
        const float4* src = reinterpret_cast<const float4*>(xr + (size_t)n0 * C_);
#pragma unroll
        for (int q = 0; q < 4; ++q) {
            int idx = tid + q * 256;
            reinterpret_cast<float4*>(s.xnl)[idx] = src[idx];
        }
        if (tid < 192)
            reinterpret_cast<uint4*>(s.cl)[tid] =
                reinterpret_cast<const uint4*>(candu + (size_t)(bN + n0) * CAND)[tid];
    }
    __syncthreads();
    int qbase = lane & ~3, qr = lane & 3;
#pragma unroll 1
    for (int si = 0; si < 6; ++si) {
        int task = w * 384 + si * 64 + lane;   // 0..1535
        int row = task / CAND, ci = task - row * CAND;
        int m = s.cl[row * CAND + ci];
        float4 buf[16];
#pragma unroll
        for (int r = 0; r < 4; ++r) {
            int mq = __shfl(m, qbase + r, 64);
            const float* xmq = xr + (size_t)mq * C_ + qr * 16;
            float4 c0 = *reinterpret_cast<const float4*>(xmq + 0);
            float4 c1 = *reinterpret_cast<const float4*>(xmq + 4);
            float4 c2 = *reinterpret_cast<const float4*>(xmq + 8);
            float4 c3 = *reinterpret_cast<const float4*>(xmq + 12);
#pragma unroll
            for (int j2 = 0; j2 < 4; ++j2) {
                float4 s0, s1, s2, s3;
                s0.x = __shfl(c0.x, qbase + j2, 64);
                s0.y = __shfl(c0.y, qbase + j2, 64);
                s0.z = __shfl(c0.z, qbase + j2, 64);
                s0.w = __shfl(c0.w, qbase + j2, 64);
                s1.x = __shfl(c1.x, qbase + j2, 64);
                s1.y = __shfl(c1.y, qbase + j2, 64);
                s1.z = __shfl(c1.z, qbase + j2, 64);
                s1.w = __shfl(c1.w, qbase + j2, 64);
                s2.x = __shfl(c2.x, qbase + j2, 64);
                s2.y = __shfl(c2.y, qbase + j2, 64);
                s2.z = __shfl(c2.z, qbase + j2, 64);
                s2.w = __shfl(c2.w, qbase + j2, 64);
                s3.x = __shfl(c3.x, qbase + j2, 64);
                s3.y = __shfl(c3.y, qbase + j2, 64);
                s3.z = __shfl(c3.z, qbase + j2, 64);
                s3.w = __shfl(c3.w, qbase + j2, 64);
                if (qr == r) {
                    buf[j2 * 4 + 0] = s0;
                    buf[j2 * 4 + 1] = s1;
                    buf[j2 * 4 + 2] = s2;
                    buf[j2 * 4 + 3] = s3;
                }
            }
        }
        const float* xn = s.xnl + row * 64;
        float a = 0.f;
#pragma unroll
        for (int cq = 0; cq < 16; ++cq) {
            float4 n4 = *reinterpret_cast<const float4*>(xn + cq * 4);
            float4 m4 = buf[cq];
            a = __fadd_rn(a, __fmul_rn(n4.x, m4.x));
            a = __fadd_rn(a, __fmul_rn(n4.y, m4.y));
            a = __fadd_rn(a, __fmul_rn(n4.z, m4.z));
            a = __fadd_rn(a, __fmul_rn(n4.w, m4.w));
        }
        s.dl2[row][ci] = __fadd_rn(__fsub_rn(sqf[bN + n0 + row], __fmul_rn(2.0f, a)),
                                   sqf[bN + m]);
    }
    __syncthreads();
#pragma unroll 1
    for (int t2 = 0; t2 < 6; ++t2) {
        int task = tid + t2 * 256;
        int row = task / CAND, ci = task - row * CAND;
        int m = s.cl[row * CAND + ci];
        float di = s.dl2[row][ci];
        int rank = 0;
#pragma unroll
        for (int j = 0; j < CAND; ++j) {
            float dj = s.dl2[row][j];
            int mj = s.cl[row * CAND + j];
            rank += (dj < di || (dj == di && mj < m)) ? 1 : 0;
        }
        if (rank < K_)
            idxf[((size_t)bN + n0 + row) * K_ + rank] = (float)m;
    }
}

__device__ __forceinline__ void ky_body(ShY& s, int bid, int tid,
                                        const float* __restrict__ x,
                                        const float* __restrict__ W,
                                        float* __restrict__ Yt) {
    int b = bid >> 5;
    int m0 = (bid & 31) * 64;
    {
        int o = tid & 63, cb = tid >> 6;
#pragma unroll
        for (int j = 0; j < 16; ++j) {
            int c = cb * 16 + j;
            s.Al[c * 64 + o] = W[o * 128 + c] - W[o * 128 + 64 + c];
            s.xl[c * 64 + o] = x[((size_t)b * C_ + c) * N_ + m0 + o];
        }
    }
    __syncthreads();
    int ml = tid & 63, og = tid >> 6;
    float acc[16];
#pragma unroll
    for (int j = 0; j < 16; ++j) acc[j] = 0.f;
#pragma unroll 4
    for (int c = 0; c < C_; ++c) {
        float xv = s.xl[c * 64 + ml];
        const float4* a4 = reinterpret_cast<const float4*>(&s.Al[c * 64 + og * 16]);
#pragma unroll
        for (int q = 0; q < 4; ++q) {
            float4 av = a4[q];
            acc[q*4+0] = fmaf(av.x, xv, acc[q*4+0]);
            acc[q*4+1] = fmaf(av.y, xv, acc[q*4+1]);
            acc[q*4+2] = fmaf(av.z, xv, acc[q*4+2]);
            acc[q*4+3] = fmaf(av.w, xv, acc[q*4+3]);
        }
    }
    float* yp = Yt + ((size_t)b * N_ + m0 + ml) * C_ + og * 16;
#pragma unroll
    for (int q = 0; q < 4; ++q)
        reinterpret_cast<float4*>(yp)[q] =
            make_float4(acc[q*4+0], acc[q*4+1], acc[q*4+2], acc[q*4+3]);
}

// K2b+K3 fat kernel (dedicated-Yt path only): blocks [0,512) rescore,
// [512,1024) Y-GEMM. LDS overlaid via union.
__global__ __launch_bounds__(256) void k_post(const float* __restrict__ xrT,
                                              const float* __restrict__ sqf,
                                              const unsigned short* __restrict__ candu,
                                              float* __restrict__ idxf,
                                              const float* __restrict__ x,
                                              const float* __restrict__ W,
                                              float* __restrict__ Yt) {
    __shared__ union U { ShR r; ShY y; } su;
    int bid = blockIdx.x;
    int tid = threadIdx.x;
    if (bid < B_ * 32)
        rescore3_body(su.r, bid, tid, xrT, sqf, candu, idxf);
    else
        ky_body(su.y, bid - B_ * 32, tid, x, W, Yt);
}

// standalone versions for the fallback paths
__global__ __launch_bounds__(256) void k_rescore3(const float* __restrict__ xrT,
                                                  const float* __restrict__ sqf,
                                                  const unsigned short* __restrict__ candu,
                                                  float* __restrict__ idxf) {
    __shared__ ShR s;
    rescore3_body(s, blockIdx.x, threadIdx.x, xrT, sqf, candu, idxf);
}

__global__ __launch_bounds__(256) void k_y(const float* __restrict__ x,
                                           const float* __restrict__ W,
                                           float* __restrict__ Yt) {
    __shared__ ShY s;
    ky_body(s, blockIdx.x, threadIdx.x, x, W, Yt);
}

// K2b fallback (xrT unavailable): exact rescore from strided x.
__global__ __launch_bounds__(256) void k_rescore(const float* __restrict__ x,
                                                 const float* __restrict__ sqf,
                                                 const unsigned short* __restrict__ candu,
                                                 float* __restrict__ idxf) {
    int tid = threadIdx.x;
    int w = tid >> 6, lane = tid & 63;
    size_t grow = (size_t)blockIdx.x * 4 + w;
    int b = (int)(grow >> 11), n = (int)(grow & (N_ - 1));
    const float* xb = x + (size_t)b * C_ * N_;
    float d = 0.f;
    unsigned m = 0xFFFFFFFFu;
    if (lane < CAND) {
        m = candu[grow * CAND + lane];
        float a = 0.f;
#pragma unroll 8
        for (int c = 0; c < C_; ++c)
            a = __fadd_rn(a, __fmul_rn(xb[(size_t)c * N_ + n], xb[(size_t)c * N_ + m]));
        d = __fadd_rn(__fsub_rn(sqf[b * N_ + n], __fmul_rn(2.0f, a)), sqf[b * N_ + m]);
    }
    int rank = 0;
#pragma unroll 1
    for (int j = 0; j < CAND; ++j) {
        float dj = __shfl(d, j, 64);
        unsigned mj = (unsigned)__shfl((int)m, j, 64);
        if (lane < CAND && (dj < d || (dj == d && mj < m))) ++rank;
    }
    if (lane < CAND && rank < K_)
        idxf[grow * K_ + rank] = (float)m;
}

// K4: Phase A u-GEMM -> Phase B wave-cooperative coalesced Yt gather-max +
// BN/leaky -> Phase C transpose store. (r16-proven form)
__global__ __launch_bounds__(256) void k_out(const float* __restrict__ x,
                                             const float* __restrict__ W,
                                             const float* __restrict__ gamma,
                                             const float* __restrict__ beta,
                                             const float* __restrict__ rmean,
                                             const float* __restrict__ rvar,
                                             const float* __restrict__ Yt,
                                             const float* __restrict__ idxf,
                                             float* __restrict__ out) {
    __shared__ float Bl[C_ * 64];
    __shared__ float xl[C_ * 64];
    __shared__ float resl[64 * 65];
    __shared__ float sl[64], tl[64];
    int tid = threadIdx.x;
    int bid = blockIdx.x;
    int b = bid >> 5;
    int n0 = (bid & 31) * 64;
    {
        int o = tid & 63, cb = tid >> 6;
#pragma unroll
        for (int j = 0; j < 16; ++j) {
            int c = cb * 16 + j;
            Bl[c * 64 + o] = W[o * 128 + 64 + c];
            xl[c * 64 + o] = x[((size_t)b * C_ + c) * N_ + n0 + o];
        }
        if (tid < 64) {
            float s = gamma[tid] / sqrtf(rvar[tid] + 1e-5f);
            sl[tid] = s;
            tl[tid] = beta[tid] - rmean[tid] * s;
        }
    }
    __syncthreads();
    {
        int nl = tid & 63, wv2 = tid >> 6;
#pragma unroll
        for (int t = 0; t < 4; ++t) {
            int oq = wv2 * 4 + t;
            float ax = 0.f, ay = 0.f, az = 0.f, aw = 0.f;
#pragma unroll 8
            for (int c = 0; c < C_; ++c) {
                float xv = xl[c * 64 + nl];
                float4 bl4 = *reinterpret_cast<const float4*>(&Bl[c * 64 + oq * 4]);
                ax = fmaf(bl4.x, xv, ax);
                ay = fmaf(bl4.y, xv, ay);
                az = fmaf(bl4.z, xv, az);
                aw = fmaf(bl4.w, xv, aw);
            }
            int o0 = oq * 4;
            resl[(o0 + 0) * 65 + nl] = ax;
            resl[(o0 + 1) * 65 + nl] = ay;
            resl[(o0 + 2) * 65 + nl] = az;
            resl[(o0 + 3) * 65 + nl] = aw;
        }
    }
    __syncthreads();
    int* mil = reinterpret_cast<int*>(Bl);    // [64][20], Bl dead
    {
#pragma unroll
        for (int q = 0; q < 5; ++q) {
            int idx = tid + q * 256;
            mil[idx] = (int)idxf[(size_t)(b * N_ + n0) * K_ + idx];
        }
    }
    __syncthreads();
    {
        int w2 = tid >> 6, lane2 = tid & 63;
        const float* Ytb = Yt + (size_t)b * N_ * C_;
        float s = sl[lane2], t0 = tl[lane2];
        for (int i = 0; i < 16; ++i) {
            int nloc = w2 * 16 + i;
            float v = -3.4e38f;
#pragma unroll
            for (int k = 0; k < K_; ++k) {
                int m = mil[nloc * K_ + k];
                v = fmaxf(v, Ytb[(size_t)m * C_ + lane2]);
            }
            float u = resl[lane2 * 65 + nloc];
            float val = s * (u + v) + t0;
            val = val > 0.f ? val : 0.2f * val;
            resl[lane2 * 65 + nloc] = val;
        }
    }
    __syncthreads();
    {
        int nl2 = tid & 63, ob = tid >> 6;
#pragma unroll
        for (int j = 0; j < 16; ++j) {
            int o2 = ob * 16 + j;
            out[((size_t)b * C_ + o2) * N_ + n0 + nl2] = resl[o2 * 65 + nl2];
        }
    }
}

extern "C" void kernel_launch(void* const* d_in, const int* in_sizes, int n_in,
                              void* d_out, int out_size, void* d_ws, size_t ws_size,
                              hipStream_t stream) {
    const float* x     = (const float*)d_in[0];
    const float* W     = (const float*)d_in[1];
    const float* gamma = (const float*)d_in[2];
    const float* beta  = (const float*)d_in[3];
    const float* rmean = (const float*)d_in[4];
    const float* rvar  = (const float*)d_in[5];

    float* out  = (float*)d_out;                         // [16][64][2048]
    float* idxf = out + (size_t)B_ * C_ * N_;            // [16][2048][20] as floats

    char* ws = (char*)d_ws;
    // layout: sqf 128K | candu u16x24 1.5M | xh 4M | xrT 8M | [Yt 8M if room]
    float* sqf            = (float*)ws;
    unsigned short* candu = (unsigned short*)(ws + 131072);
    unsigned short* xh    = (unsigned short*)(ws + 131072 + 1572864);
    size_t off_xrT        = 131072 + 1572864 + 4194304;              // 5.90 MB
    size_t need_xrT       = off_xrT + 8388608;                       // 14.28 MB
    size_t need_ded       = need_xrT + 8388608;                      // 22.68 MB
    float* xrT            = (ws_size >= need_xrT) ? (float*)(ws + off_xrT) : nullptr;
    bool dedY             = (ws_size >= need_ded);
    float* Yt             = dedY ? (float*)(ws + need_xrT) : (float*)(ws + 131072);

    k_sq   <<<B_ * N_ / 128, 128, 0, stream>>>(x, sqf, xh, xrT);
    k_dist <<<B_ * 32, 256, 0, stream>>>(xh, sqf, candu);
    if (xrT && dedY) {
        k_post<<<B_ * 64, 256, 0, stream>>>(xrT, sqf, candu, idxf, x, W, Yt);
    } else if (xrT) {
        k_rescore3<<<B_ * 32, 256, 0, stream>>>(xrT, sqf, candu, idxf);
        k_y<<<B_ * 32, 256, 0, stream>>>(x, W, Yt);
    } else {
        k_rescore<<<B_ * N_ / 4, 256, 0, stream>>>(x, sqf, candu, idxf);
        k_y<<<B_ * 32, 256, 0, stream>>>(x, W, Yt);
    }
    k_out  <<<B_ * 32, 256, 0, stream>>>(x, W, gamma, beta, rmean, rvar, Yt, idxf, out);
}

// Round 20
// 150.078 us; speedup vs baseline: 1.6969x; 1.0118x over previous
//
#include <hip/hip_runtime.h>
#include <cstdint>
#include <cstddef>

#define B_ 16
#define C_ 64
#define N_ 2048
#define K_ 20
#define CAND 24
#define LQ 12

typedef short bf16x8 __attribute__((ext_vector_type(8)));
typedef float f32x4 __attribute__((ext_vector_type(4)));

__device__ __forceinline__ unsigned umin_(unsigned a, unsigned b) { return a < b ? a : b; }
__device__ __forceinline__ unsigned umax_(unsigned a, unsigned b) { return a > b ? a : b; }
__device__ __forceinline__ unsigned short bfr_(float v) {
    unsigned u = __float_as_uint(v);
    return (unsigned short)((u + 0x7FFFu + ((u >> 16) & 1u)) >> 16);
}

// K1 (lean): sqf = np.sum(xt*xt,-1) bit-exact (pairwise 8-acc tree);
// xh = bf16 rows, c-blocks XOR-swizzled; xrT = f32 contiguous rows.
__global__ __launch_bounds__(128) void k_sq(const float* __restrict__ x,
                                            float* __restrict__ sqf,
                                            unsigned short* __restrict__ xh,
                                            float* __restrict__ xrT) {
    int tid = threadIdx.x;
    int i = blockIdx.x * 128 + tid;   // 0..B_*N_-1
    int b = i >> 11, n = i & (N_ - 1);
    const float* xb = x + (size_t)b * C_ * N_ + n;
    float vr[C_];
#pragma unroll
    for (int c = 0; c < C_; ++c) vr[c] = xb[(size_t)c * N_];
    float p[C_];
#pragma unroll
    for (int c = 0; c < C_; ++c) p[c] = __fmul_rn(vr[c], vr[c]);
    float r[8];
#pragma unroll
    for (int k = 0; k < 8; ++k) r[k] = p[k];
#pragma unroll
    for (int ii = 8; ii < 64; ii += 8) {
#pragma unroll
        for (int k = 0; k < 8; ++k) r[k] = __fadd_rn(r[k], p[ii + k]);
    }
    float s0 = __fadd_rn(__fadd_rn(r[0], r[1]), __fadd_rn(r[2], r[3]));
    float s1 = __fadd_rn(__fadd_rn(r[4], r[5]), __fadd_rn(r[6], r[7]));
    sqf[i] = __fadd_rn(s0, s1);

    unsigned short* xrow = xh + (size_t)i * 64;
#pragma unroll
    for (int cb = 0; cb < 8; ++cb) {
        bf16x8 pk;
#pragma unroll
        for (int e = 0; e < 8; ++e) pk[e] = (short)bfr_(vr[cb * 8 + e]);
        *reinterpret_cast<bf16x8*>(xrow + ((cb ^ (n & 7)) * 8)) = pk;
    }
    if (xrT) {
        float4* dst = reinterpret_cast<float4*>(xrT + (size_t)i * C_);
#pragma unroll
        for (int q = 0; q < 16; ++q)
            dst[q] = make_float4(vr[q*4+0], vr[q*4+1], vr[q*4+2], vr[q*4+3]);
    }
}

// K2a: MFMA distance pass. r19 structure, but each row's sorted-insert is ONE
// asm block (11 med3 + 1 min, 12 tied operands) — no inter-statement asm
// boundaries, so the allocator cannot insert v_mov shuffles between steps.
__global__ __launch_bounds__(256, 2) void k_dist(const unsigned short* __restrict__ xh,
                                                 const float* __restrict__ sqf,
                                                 unsigned short* __restrict__ candu) {
    __shared__ __align__(16) unsigned short xtl[256 * 64];   // 32 KB
    __shared__ float sqm[256];
    int tid = threadIdx.x;
    int w = tid >> 6, lane = tid & 63;
    int bid = blockIdx.x;             // B_*32 = 512
    int b = bid >> 5;
    int n0 = (bid & 31) * 64;
    const unsigned short* xhb = xh + (size_t)b * N_ * 64;

    {
#pragma unroll
        for (int i = 0; i < 2; ++i) {
            int ch = tid + 256 * i;
            *reinterpret_cast<uint4*>(&xtl[ch * 8]) =
                *reinterpret_cast<const uint4*>(&xhb[(size_t)n0 * 64 + ch * 8]);
        }
    }
    __syncthreads();
    int rl = w * 16 + (lane & 15);
    int cb0 = (lane >> 4), cb1 = 4 + (lane >> 4);
    bf16x8 afr0 = *reinterpret_cast<const bf16x8*>(&xtl[rl * 64 + ((cb0 ^ (lane & 7)) * 8)]);
    bf16x8 afr1 = *reinterpret_cast<const bf16x8*>(&xtl[rl * 64 + ((cb1 ^ (lane & 7)) * 8)]);
    float rsq[4];
#pragma unroll
    for (int r = 0; r < 4; ++r)
        rsq[r] = sqf[b * N_ + n0 + w * 16 + (lane >> 4) * 4 + r];

    unsigned list[4][LQ];
#pragma unroll
    for (int r = 0; r < 4; ++r)
#pragma unroll
        for (int j = 0; j < LQ; ++j) list[r][j] = 0xFFFFFFFFu;

    unsigned kmask = 0xFFFFF800u;

    for (int t = 0; t < 8; ++t) {
        int m0 = t * 256;
        __syncthreads();
        {
#pragma unroll
            for (int i = 0; i < 8; ++i) {
                int ch = tid + 256 * i;
                *reinterpret_cast<uint4*>(&xtl[ch * 8]) =
                    *reinterpret_cast<const uint4*>(&xhb[(size_t)m0 * 64 + ch * 8]);
            }
            sqm[tid] = sqf[b * N_ + m0 + tid];
        }
        __syncthreads();
        // AGPR-home ban: anything live across this point stays in arch VGPRs.
        asm volatile("" :::
            "a0","a1","a2","a3","a4","a5","a6","a7",
            "a8","a9","a10","a11","a12","a13","a14","a15",
            "a16","a17","a18","a19","a20","a21","a22","a23",
            "a24","a25","a26","a27","a28","a29","a30","a31",
            "a32","a33","a34","a35","a36","a37","a38","a39",
            "a40","a41","a42","a43","a44","a45","a46","a47",
            "a48","a49","a50","a51","a52","a53","a54","a55",
            "a56","a57","a58","a59","a60","a61","a62","a63",
            "a64","a65","a66","a67","a68","a69","a70","a71",
            "a72","a73","a74","a75","a76","a77","a78","a79",
            "a80","a81","a82","a83","a84","a85","a86","a87",
            "a88","a89","a90","a91","a92","a93","a94","a95");
        const unsigned short* pB0 = &xtl[(lane & 15) * 64 + ((cb0 ^ (lane & 7)) * 8)];
        const unsigned short* pB1 = &xtl[(lane & 15) * 64 + ((cb1 ^ (lane & 7)) * 8)];
        const float* pS = &sqm[lane & 15];
#pragma unroll
        for (int mb = 0; mb < 16; ++mb) {
            bf16x8 bf0 = *reinterpret_cast<const bf16x8*>(pB0 + mb * 1024);
            bf16x8 bf1 = *reinterpret_cast<const bf16x8*>(pB1 + mb * 1024);
            f32x4 acc = {0.f, 0.f, 0.f, 0.f};
            acc = __builtin_amdgcn_mfma_f32_16x16x32_bf16(afr0, bf0, acc, 0, 0, 0);
            acc = __builtin_amdgcn_mfma_f32_16x16x32_bf16(afr1, bf1, acc, 0, 0, 0);
            float smv = pS[mb * 16];
            unsigned mg = (unsigned)(m0 + mb * 16) | (unsigned)(lane & 15);
#pragma unroll
            for (int r = 0; r < 4; ++r) {
                float rs = rsq[r] + smv;
                float d = fmaf(-2.f, acc[r], rs);
                d = fmaxf(d, 0.f);   // d>=0: IEEE bits are unsigned-monotone
                unsigned key;
                asm("v_bfi_b32 %0, %1, %2, %3"
                    : "=v"(key) : "v"(kmask), "v"(__float_as_uint(d)), "v"(mg));
                // whole sorted-insert as ONE asm block: no boundary copies
                asm("v_med3_u32 %11, %11, %10, %12\n\t"
                    "v_med3_u32 %10, %10, %9, %12\n\t"
                    "v_med3_u32 %9, %9, %8, %12\n\t"
                    "v_med3_u32 %8, %8, %7, %12\n\t"
                    "v_med3_u32 %7, %7, %6, %12\n\t"
                    "v_med3_u32 %6, %6, %5, %12\n\t"
                    "v_med3_u32 %5, %5, %4, %12\n\t"
                    "v_med3_u32 %4, %4, %3, %12\n\t"
                    "v_med3_u32 %3, %3, %2, %12\n\t"
                    "v_med3_u32 %2, %2, %1, %12\n\t"
                    "v_med3_u32 %1, %1, %0, %12\n\t"
                    "v_min_u32 %0, %0, %12"
                    : "+v"(list[r][0]), "+v"(list[r][1]), "+v"(list[r][2]),
                      "+v"(list[r][3]), "+v"(list[r][4]), "+v"(list[r][5]),
                      "+v"(list[r][6]), "+v"(list[r][7]), "+v"(list[r][8]),
                      "+v"(list[r][9]), "+v"(list[r][10]), "+v"(list[r][11])
                    : "v"(key));
            }
        }
    }

    size_t grow0 = (size_t)b * N_ + n0 + w * 16 + (lane >> 4) * 4;
#pragma unroll 1
    for (int it = 0; it < CAND; ++it) {
        unsigned head[4], wv[4];
#pragma unroll
        for (int j = 0; j < 4; ++j) { head[j] = list[j][0]; wv[j] = head[j]; }
#pragma unroll
        for (int d2 = 1; d2 < 16; d2 <<= 1)
#pragma unroll
            for (int j = 0; j < 4; ++j)
                wv[j] = umin_(wv[j], (unsigned)__shfl_xor((int)wv[j], d2, 16));
#pragma unroll
        for (int j = 0; j < 4; ++j) {
            bool own = (head[j] == wv[j]);
#pragma unroll
            for (int jj = 0; jj < LQ - 1; ++jj)
                list[j][jj] = own ? list[j][jj + 1] : list[j][jj];
            list[j][LQ - 1] = own ? 0xFFFFFFFFu : list[j][LQ - 1];
            if ((lane & 15) == 0)
                candu[(grow0 + j) * CAND + it] = (unsigned short)(wv[j] & 2047u);
        }
    }
}

// shared bodies for rescore3 / k_y --------------------------------------

struct ShR { float xnl[64 * 64]; unsigned short cl[64 * CAND]; float dl2[64][CAND]; };
struct ShY { float Al[C_ * 64]; float xl[C_ * 64]; };

__device__ __forceinline__ void rescore3_body(ShR& s, int bid, int tid,
                                              const float* __restrict__ xrT,
                                              const float* __restrict__ sqf,
                                              const unsigned short* __restrict__ candu,
                                              float* __restrict__ idxf) {
    int lane = tid & 63, w = tid >> 6;
    int b = bid >> 5;
    int n0 = (bid & 31) * 64;
    int bN = b * N_;
    const float* xr = xrT + (size_t)bN * C_;
    {
        const float4* src = reinterpret_cast<const float4*>(xr + (size_t)n0 * C_);
#pragma unroll
        for (int q = 0; q < 4; ++q) {
            int idx = tid + q * 256;
            reinterpret_cast<float4*>(s.xnl)[idx] = src[idx];
        }
        if (tid < 192)
            reinterpret_cast<uint4*>(s.cl)[tid] =
                reinterpret_cast<const uint4*>(candu + (size_t)(bN + n0) * CAND)[tid];
    }
    __syncthreads();
    int qbase = lane & ~3, qr = lane & 3;
#pragma unroll 1
    for (int si = 0; si < 6; ++si) {
        int task = w * 384 + si * 64 + lane;   // 0..1535
        int row = task / CAND, ci = task - row * CAND;
        int m = s.cl[row * CAND + ci];
        float4 buf[16];
#pragma unroll
        for (int r = 0; r < 4; ++r) {
            int mq = __shfl(m, qbase + r, 64);
            const float* xmq = xr + (size_t)mq * C_ + qr * 16;
            float4 c0 = *reinterpret_cast<const float4*>(xmq + 0);
            float4 c1 = *reinterpret_cast<const float4*>(xmq + 4);
            float4 c2 = *reinterpret_cast<const float4*>(xmq + 8);
            float4 c3 = *reinterpret_cast<const float4*>(xmq + 12);
#pragma unroll
            for (int j2 = 0; j2 < 4; ++j2) {
                float4 s0, s1, s2, s3;
                s0.x = __shfl(c0.x, qbase + j2, 64);
                s0.y = __shfl(c0.y, qbase + j2, 64);
                s0.z = __shfl(c0.z, qbase + j2, 64);
                s0.w = __shfl(c0.w, qbase + j2, 64);
                s1.x = __shfl(c1.x, qbase + j2, 64);
                s1.y = __shfl(c1.y, qbase + j2, 64);
                s1.z = __shfl(c1.z, qbase + j2, 64);
                s1.w = __shfl(c1.w, qbase + j2, 64);
                s2.x = __shfl(c2.x, qbase + j2, 64);
                s2.y = __shfl(c2.y, qbase + j2, 64);
                s2.z = __shfl(c2.z, qbase + j2, 64);
                s2.w = __shfl(c2.w, qbase + j2, 64);
                s3.x = __shfl(c3.x, qbase + j2, 64);
                s3.y = __shfl(c3.y, qbase + j2, 64);
                s3.z = __shfl(c3.z, qbase + j2, 64);
                s3.w = __shfl(c3.w, qbase + j2, 64);
                if (qr == r) {
                    buf[j2 * 4 + 0] = s0;
                    buf[j2 * 4 + 1] = s1;
                    buf[j2 * 4 + 2] = s2;
                    buf[j2 * 4 + 3] = s3;
                }
            }
        }
        const float* xn = s.xnl + row * 64;
        float a = 0.f;
#pragma unroll
        for (int cq = 0; cq < 16; ++cq) {
            float4 n4 = *reinterpret_cast<const float4*>(xn + cq * 4);
            float4 m4 = buf[cq];
            a = __fadd_rn(a, __fmul_rn(n4.x, m4.x));
            a = __fadd_rn(a, __fmul_rn(n4.y, m4.y));
            a = __fadd_rn(a, __fmul_rn(n4.z, m4.z));
            a = __fadd_rn(a, __fmul_rn(n4.w, m4.w));
        }
        s.dl2[row][ci] = __fadd_rn(__fsub_rn(sqf[bN + n0 + row], __fmul_rn(2.0f, a)),
                                   sqf[bN + m]);
    }
    __syncthreads();
#pragma unroll 1
    for (int t2 = 0; t2 < 6; ++t2) {
        int task = tid + t2 * 256;
        int row = task / CAND, ci = task - row * CAND;
        int m = s.cl[row * CAND + ci];
        float di = s.dl2[row][ci];
        int rank = 0;
#pragma unroll
        for (int j = 0; j < CAND; ++j) {
            float dj = s.dl2[row][j];
            int mj = s.cl[row * CAND + j];
            rank += (dj < di || (dj == di && mj < m)) ? 1 : 0;
        }
        if (rank < K_)
            idxf[((size_t)bN + n0 + row) * K_ + rank] = (float)m;
    }
}

__device__ __forceinline__ void ky_body(ShY& s, int bid, int tid,
                                        const float* __restrict__ x,
                                        const float* __restrict__ W,
                                        float* __restrict__ Yt) {
    int b = bid >> 5;
    int m0 = (bid & 31) * 64;
    {
        int o = tid & 63, cb = tid >> 6;
#pragma unroll
        for (int j = 0; j < 16; ++j) {
            int c = cb * 16 + j;
            s.Al[c * 64 + o] = W[o * 128 + c] - W[o * 128 + 64 + c];
            s.xl[c * 64 + o] = x[((size_t)b * C_ + c) * N_ + m0 + o];
        }
    }
    __syncthreads();
    int ml = tid & 63, og = tid >> 6;
    float acc[16];
#pragma unroll
    for (int j = 0; j < 16; ++j) acc[j] = 0.f;
#pragma unroll 4
    for (int c = 0; c < C_; ++c) {
        float xv = s.xl[c * 64 + ml];
        const float4* a4 = reinterpret_cast<const float4*>(&s.Al[c * 64 + og * 16]);
#pragma unroll
        for (int q = 0; q < 4; ++q) {
            float4 av = a4[q];
            acc[q*4+0] = fmaf(av.x, xv, acc[q*4+0]);
            acc[q*4+1] = fmaf(av.y, xv, acc[q*4+1]);
            acc[q*4+2] = fmaf(av.z, xv, acc[q*4+2]);
            acc[q*4+3] = fmaf(av.w, xv, acc[q*4+3]);
        }
    }
    float* yp = Yt + ((size_t)b * N_ + m0 + ml) * C_ + og * 16;
#pragma unroll
    for (int q = 0; q < 4; ++q)
        reinterpret_cast<float4*>(yp)[q] =
            make_float4(acc[q*4+0], acc[q*4+1], acc[q*4+2], acc[q*4+3]);
}

// K2b+K3 fat kernel (dedicated-Yt path only): blocks [0,512) rescore,
// [512,1024) Y-GEMM. LDS overlaid via union.
__global__ __launch_bounds__(256) void k_post(const float* __restrict__ xrT,
                                              const float* __restrict__ sqf,
                                              const unsigned short* __restrict__ candu,
                                              float* __restrict__ idxf,
                                              const float* __restrict__ x,
                                              const float* __restrict__ W,
                                              float* __restrict__ Yt) {
    __shared__ union U { ShR r; ShY y; } su;
    int bid = blockIdx.x;
    int tid = threadIdx.x;
    if (bid < B_ * 32)
        rescore3_body(su.r, bid, tid, xrT, sqf, candu, idxf);
    else
        ky_body(su.y, bid - B_ * 32, tid, x, W, Yt);
}

// standalone versions for the fallback paths
__global__ __launch_bounds__(256) void k_rescore3(const float* __restrict__ xrT,
                                                  const float* __restrict__ sqf,
                                                  const unsigned short* __restrict__ candu,
                                                  float* __restrict__ idxf) {
    __shared__ ShR s;
    rescore3_body(s, blockIdx.x, threadIdx.x, xrT, sqf, candu, idxf);
}

__global__ __launch_bounds__(256) void k_y(const float* __restrict__ x,
                                           const float* __restrict__ W,
                                           float* __restrict__ Yt) {
    __shared__ ShY s;
    ky_body(s, blockIdx.x, threadIdx.x, x, W, Yt);
}

// K2b fallback (xrT unavailable): exact rescore from strided x.
__global__ __launch_bounds__(256) void k_rescore(const float* __restrict__ x,
                                                 const float* __restrict__ sqf,
                                                 const unsigned short* __restrict__ candu,
                                                 float* __restrict__ idxf) {
    int tid = threadIdx.x;
    int w = tid >> 6, lane = tid & 63;
    size_t grow = (size_t)blockIdx.x * 4 + w;
    int b = (int)(grow >> 11), n = (int)(grow & (N_ - 1));
    const float* xb = x + (size_t)b * C_ * N_;
    float d = 0.f;
    unsigned m = 0xFFFFFFFFu;
    if (lane < CAND) {
        m = candu[grow * CAND + lane];
        float a = 0.f;
#pragma unroll 8
        for (int c = 0; c < C_; ++c)
            a = __fadd_rn(a, __fmul_rn(xb[(size_t)c * N_ + n], xb[(size_t)c * N_ + m]));
        d = __fadd_rn(__fsub_rn(sqf[b * N_ + n], __fmul_rn(2.0f, a)), sqf[b * N_ + m]);
    }
    int rank = 0;
#pragma unroll 1
    for (int j = 0; j < CAND; ++j) {
        float dj = __shfl(d, j, 64);
        unsigned mj = (unsigned)__shfl((int)m, j, 64);
        if (lane < CAND && (dj < d || (dj == d && mj < m))) ++rank;
    }
    if (lane < CAND && rank < K_)
        idxf[grow * K_ + rank] = (float)m;
}

// K4: Phase A u-GEMM -> Phase B wave-cooperative coalesced Yt gather-max +
// BN/leaky -> Phase C transpose store. (r16-proven form)
__global__ __launch_bounds__(256) void k_out(const float* __restrict__ x,
                                             const float* __restrict__ W,
                                             const float* __restrict__ gamma,
                                             const float* __restrict__ beta,
                                             const float* __restrict__ rmean,
                                             const float* __restrict__ rvar,
                                             const float* __restrict__ Yt,
                                             const float* __restrict__ idxf,
                                             float* __restrict__ out) {
    __shared__ float Bl[C_ * 64];
    __shared__ float xl[C_ * 64];
    __shared__ float resl[64 * 65];
    __shared__ float sl[64], tl[64];
    int tid = threadIdx.x;
    int bid = blockIdx.x;
    int b = bid >> 5;
    int n0 = (bid & 31) * 64;
    {
        int o = tid & 63, cb = tid >> 6;
#pragma unroll
        for (int j = 0; j < 16; ++j) {
            int c = cb * 16 + j;
            Bl[c * 64 + o] = W[o * 128 + 64 + c];
            xl[c * 64 + o] = x[((size_t)b * C_ + c) * N_ + n0 + o];
        }
        if (tid < 64) {
            float s = gamma[tid] / sqrtf(rvar[tid] + 1e-5f);
            sl[tid] = s;
            tl[tid] = beta[tid] - rmean[tid] * s;
        }
    }
    __syncthreads();
    {
        int nl = tid & 63, wv2 = tid >> 6;
#pragma unroll
        for (int t = 0; t < 4; ++t) {
            int oq = wv2 * 4 + t;
            float ax = 0.f, ay = 0.f, az = 0.f, aw = 0.f;
#pragma unroll 8
            for (int c = 0; c < C_; ++c) {
                float xv = xl[c * 64 + nl];
                float4 bl4 = *reinterpret_cast<const float4*>(&Bl[c * 64 + oq * 4]);
                ax = fmaf(bl4.x, xv, ax);
                ay = fmaf(bl4.y, xv, ay);
                az = fmaf(bl4.z, xv, az);
                aw = fmaf(bl4.w, xv, aw);
            }
            int o0 = oq * 4;
            resl[(o0 + 0) * 65 + nl] = ax;
            resl[(o0 + 1) * 65 + nl] = ay;
            resl[(o0 + 2) * 65 + nl] = az;
            resl[(o0 + 3) * 65 + nl] = aw;
        }
    }
    __syncthreads();
    int* mil = reinterpret_cast<int*>(Bl);    // [64][20], Bl dead
    {
#pragma unroll
        for (int q = 0; q < 5; ++q) {
            int idx = tid + q * 256;
            mil[idx] = (int)idxf[(size_t)(b * N_ + n0) * K_ + idx];
        }
    }
    __syncthreads();
    {
        int w2 = tid >> 6, lane2 = tid & 63;
        const float* Ytb = Yt + (size_t)b * N_ * C_;
        float s = sl[lane2], t0 = tl[lane2];
        for (int i = 0; i < 16; ++i) {
            int nloc = w2 * 16 + i;
            float v = -3.4e38f;
#pragma unroll
            for (int k = 0; k < K_; ++k) {
                int m = mil[nloc * K_ + k];
                v = fmaxf(v, Ytb[(size_t)m * C_ + lane2]);
            }
            float u = resl[lane2 * 65 + nloc];
            float val = s * (u + v) + t0;
            val = val > 0.f ? val : 0.2f * val;
            resl[lane2 * 65 + nloc] = val;
        }
    }
    __syncthreads();
    {
        int nl2 = tid & 63, ob = tid >> 6;
#pragma unroll
        for (int j = 0; j < 16; ++j) {
            int o2 = ob * 16 + j;
            out[((size_t)b * C_ + o2) * N_ + n0 + nl2] = resl[o2 * 65 + nl2];
        }
    }
}

extern "C" void kernel_launch(void* const* d_in, const int* in_sizes, int n_in,
                              void* d_out, int out_size, void* d_ws, size_t ws_size,
                              hipStream_t stream) {
    const float* x     = (const float*)d_in[0];
    const float* W     = (const float*)d_in[1];
    const float* gamma = (const float*)d_in[2];
    const float* beta  = (const float*)d_in[3];
    const float* rmean = (const float*)d_in[4];
    const float* rvar  = (const float*)d_in[5];

    float* out  = (float*)d_out;                         // [16][64][2048]
    float* idxf = out + (size_t)B_ * C_ * N_;            // [16][2048][20] as floats

    char* ws = (char*)d_ws;
    // layout: sqf 128K | candu u16x24 1.5M | xh 4M | xrT 8M | [Yt 8M if room]
    float* sqf            = (float*)ws;
    unsigned short* candu = (unsigned short*)(ws + 131072);
    unsigned short* xh    = (unsigned short*)(ws + 131072 + 1572864);
    size_t off_xrT        = 131072 + 1572864 + 4194304;              // 5.90 MB
    size_t need_xrT       = off_xrT + 8388608;                       // 14.28 MB
    size_t need_ded       = need_xrT + 8388608;                      // 22.68 MB
    float* xrT            = (ws_size >= need_xrT) ? (float*)(ws + off_xrT) : nullptr;
    bool dedY             = (ws_size >= need_ded);
    float* Yt             = dedY ? (float*)(ws + need_xrT) : (float*)(ws + 131072);

    k_sq   <<<B_ * N_ / 128, 128, 0, stream>>>(x, sqf, xh, xrT);
    k_dist <<<B_ * 32, 256, 0, stream>>>(xh, sqf, candu);
    if (xrT && dedY) {
        k_post<<<B_ * 64, 256, 0, stream>>>(xrT, sqf, candu, idxf, x, W, Yt);
    } else if (xrT) {
        k_rescore3<<<B_ * 32, 256, 0, stream>>>(xrT, sqf, candu, idxf);
        k_y<<<B_ * 32, 256, 0, stream>>>(x, W, Yt);
    } else {
        k_rescore<<<B_ * N_ / 4, 256, 0, stream>>>(x, sqf, candu, idxf);
        k_y<<<B_ * 32, 256, 0, stream>>>(x, W, Yt);
    }
    k_out  <<<B_ * 32, 256, 0, stream>>>(x, W, gamma, beta, rmean, rvar, Yt, idxf, out);
}